// Round 7
// baseline (138.735 us; speedup 1.0000x reference)
//
#include <hip/hip_runtime.h>
#include <hip/hip_bf16.h>
#include <math.h>

#define DIM  64
#define KN   16
#define NREL 32

__device__ __forceinline__ float frcp(float x) { return __builtin_amdgcn_rcpf(x); }

__device__ __forceinline__ unsigned short f2bf(float f) {
    unsigned u = __float_as_uint(f);
    u = (u + 0x7fffu + ((u >> 16) & 1u)) >> 16;   // RNE
    return (unsigned short)u;
}
// bf16 pair packed in a dword: low ushort = even dim, high ushort = odd dim
__device__ __forceinline__ float bflo(unsigned v) { return __uint_as_float(v << 16); }
__device__ __forceinline__ float bfhi(unsigned v) { return __uint_as_float(v & 0xffff0000u); }

// global -> LDS DMA, 4 B per lane, zero VGPR data cost. LDS dest must be
// wave-uniform; global src is per-lane.
__device__ __forceinline__ void gload_lds4(const void* g, void* l) {
    __builtin_amdgcn_global_load_lds(
        (const __attribute__((address_space(1))) unsigned int*)g,
        (__attribute__((address_space(3))) unsigned int*)l, 4, 0, 0);
}

typedef __attribute__((ext_vector_type(8))) short bfrag;   // 8 bf16 (4 VGPRs)
typedef __attribute__((ext_vector_type(4))) float f32x4;   // MFMA accumulator

// ============================================================================
// Kernel 1 (R16, verified): WE precompute as MFMA GEMM + adjacency packing
// adjP[i] = (adjE[i]<<5) | adjR[i].
// ============================================================================
__global__ __launch_bounds__(256, 2) void we_kernel_mfma(
    const float* __restrict__ entity_emb,
    const float* __restrict__ W,
    const int* __restrict__ adjE,
    const int* __restrict__ adjR,
    unsigned short* __restrict__ WEb,
    int* __restrict__ adjP,
    int nRows)
{
    const int tid  = threadIdx.x;
    const int wave = tid >> 6;
    const int lane = tid & 63;
    const int c = lane & 15;
    const int g = lane >> 4;

    // ---- pack adjacency: 8 entries per thread, int4 vectorized ----
    {
        const size_t nEntries = (size_t)nRows * KN;
        const size_t base = ((size_t)blockIdx.x * 256 + tid) * 8;
        if (base + 8 <= nEntries) {
            const int4* e4 = (const int4*)(adjE + base);
            const int4* r4 = (const int4*)(adjR + base);
            const int4 e0 = e4[0], e1v = e4[1];
            const int4 r0 = r4[0], r1v = r4[1];
            int4 p0, p1;
            p0.x = (e0.x << 5) | r0.x;  p0.y = (e0.y << 5) | r0.y;
            p0.z = (e0.z << 5) | r0.z;  p0.w = (e0.w << 5) | r0.w;
            p1.x = (e1v.x << 5) | r1v.x; p1.y = (e1v.y << 5) | r1v.y;
            p1.z = (e1v.z << 5) | r1v.z; p1.w = (e1v.w << 5) | r1v.w;
            ((int4*)(adjP + base))[0] = p0;
            ((int4*)(adjP + base))[1] = p1;
        } else if (base < nEntries) {
            for (size_t i = base; i < nEntries; ++i)
                adjP[i] = (adjE[i] << 5) | adjR[i];
        }
    }

    const int nTiles = (nRows + 15) >> 4;
    const int t0 = (blockIdx.x * 4 + wave) * 2;       // 2 tiles per wave
    if (t0 >= nTiles) return;

    bfrag a[4][2];
    #pragma unroll
    for (int m = 0; m < 4; ++m) {
        #pragma unroll
        for (int ks = 0; ks < 2; ++ks) {
            const float4* ws = (const float4*)(W + (size_t)(16 * m + c) * DIM + 8 * g + 32 * ks);
            const float4 w0 = ws[0], w1 = ws[1];
            a[m][ks][0] = (short)f2bf(w0.x); a[m][ks][1] = (short)f2bf(w0.y);
            a[m][ks][2] = (short)f2bf(w0.z); a[m][ks][3] = (short)f2bf(w0.w);
            a[m][ks][4] = (short)f2bf(w1.x); a[m][ks][5] = (short)f2bf(w1.y);
            a[m][ks][6] = (short)f2bf(w1.z); a[m][ks][7] = (short)f2bf(w1.w);
        }
    }

    float4 pe[2][4];
    #pragma unroll
    for (int j = 0; j < 2; ++j) {
        const int t = (t0 + j < nTiles) ? (t0 + j) : 0;
        int row = 16 * t + c;
        if (row >= nRows) row = nRows - 1;
        const float4* src = (const float4*)(entity_emb + (size_t)row * DIM + 8 * g);
        pe[j][0] = src[0];
        pe[j][1] = src[1];
        pe[j][2] = src[8];
        pe[j][3] = src[9];
    }

    #pragma unroll
    for (int j = 0; j < 2; ++j) {
        const int t = t0 + j;
        if (t >= nTiles) continue;

        bfrag b0, b1;
        b0[0] = (short)f2bf(pe[j][0].x); b0[1] = (short)f2bf(pe[j][0].y);
        b0[2] = (short)f2bf(pe[j][0].z); b0[3] = (short)f2bf(pe[j][0].w);
        b0[4] = (short)f2bf(pe[j][1].x); b0[5] = (short)f2bf(pe[j][1].y);
        b0[6] = (short)f2bf(pe[j][1].z); b0[7] = (short)f2bf(pe[j][1].w);
        b1[0] = (short)f2bf(pe[j][2].x); b1[1] = (short)f2bf(pe[j][2].y);
        b1[2] = (short)f2bf(pe[j][2].z); b1[3] = (short)f2bf(pe[j][2].w);
        b1[4] = (short)f2bf(pe[j][3].x); b1[5] = (short)f2bf(pe[j][3].y);
        b1[6] = (short)f2bf(pe[j][3].z); b1[7] = (short)f2bf(pe[j][3].w);

        f32x4 acc[4];
        #pragma unroll
        for (int m = 0; m < 4; ++m) {
            f32x4 z = {0.f, 0.f, 0.f, 0.f};
            z = __builtin_amdgcn_mfma_f32_16x16x32_bf16(a[m][0], b0, z, 0, 0, 0);
            z = __builtin_amdgcn_mfma_f32_16x16x32_bf16(a[m][1], b1, z, 0, 0, 0);
            acc[m] = z;
        }

        const int erow = 16 * t + c;
        if (erow < nRows) {
            #pragma unroll
            for (int m = 0; m < 4; ++m) {
                const unsigned lo = (unsigned)f2bf(acc[m][0]) | ((unsigned)f2bf(acc[m][1]) << 16);
                const unsigned hi = (unsigned)f2bf(acc[m][2]) | ((unsigned)f2bf(acc[m][3]) << 16);
                *(uint2*)(WEb + (size_t)erow * DIM + 16 * m + 4 * g) = make_uint2(lo, hi);
            }
        }
    }
}

// ============================================================================
// Kernel 2 (R17): hop-1 neighbor gathers via global_load_lds DMA.
// Per slot s: 64 rows (4 quarters x 16 neighbors) fetched by 32 DMA
// instructions (64 lanes x 4B = 2 rows each) into an 8 KB per-wave LDS
// buffer — all 32 in flight simultaneously, ZERO VGPR data cost. This
// breaks the VGPR ceiling that limited outstanding loads to ~2/wave
// (R14/R15/R16 all flat). vmcnt(0) + LDS consume per slot; cross-wave
// overlap (12 waves/CU) covers the per-slot latency.
// ============================================================================
__global__ __launch_bounds__(256, 3) void kgcn_main(
    const int* __restrict__ pairs,
    const int* __restrict__ adjP,
    const unsigned short* __restrict__ WEb,
    const float* __restrict__ relation_emb,
    const float* __restrict__ user_emb,
    const float* __restrict__ W,
    const float* __restrict__ bias,
    float* __restrict__ out,
    int nPairs)
{
    __shared__ uint2 gbuf_s[4][64 * 16];  // 8 KB/wave DMA landing buffer
    __shared__ float ev1_s[4][KN * DIM];  // per-wave layer-0 outputs
    __shared__ float xb_s[4][DIM];        // per-wave matvec broadcast buffer

    const int tid  = threadIdx.x;
    const int wave = tid >> 6;
    const int lane = tid & 63;
    const int p    = blockIdx.x * 4 + wave;
    if (p >= nPairs) return;              // wave-uniform, no barriers -> safe

    uint2* gbuf = gbuf_s[wave];
    float* ev1  = ev1_s[wave];
    float* xb   = xb_s[wave];

    const int qq = lane >> 4;             // quarter-wave id (0..3)
    const int c  = lane & 15;             // uint2 column within a WE row
    const int c4 = c * 4;                 // first owned dim

    const int user = pairs[2 * p + 0];
    const int item = pairs[2 * p + 1];

    const float4 b4 = *(const float4*)(bias + c4);
    const float bl = bias[lane];          // for the final matvec (load early)
    const uint2* WEq = (const uint2*)WEb;

    // ---- chase root: item packed adjacency row ----
    int rk0 = 0, e1 = 0;
    if (lane < KN) {
        const int pk0 = adjP[(size_t)item * KN + lane];
        rk0 = pk0 & 31;
        e1  = pk0 >> 5;
    }

    // ---- independent: user/relation rows into regs ----
    float4 rr[8], ur[8];
    {
        const int r = lane >> 1, hlf = lane & 1;
        const float4* rel4 = (const float4*)(relation_emb + r * DIM + hlf * 32);
        const float4* u4   = (const float4*)(user_emb + (size_t)user * DIM + hlf * 32);
        #pragma unroll
        for (int j = 0; j < 8; ++j) { rr[j] = rel4[j]; ur[j] = u4[j]; }
    }

    // ---- e1 arrival gates: hop-0 rows + slot adjacency + self rows ----
    const uint2 itemv = WEq[(size_t)item * 16 + c];
    uint2 h0v[4];
    #pragma unroll
    for (int k = 0; k < 4; ++k) {
        const int e = __shfl(e1, qq * 4 + k);
        h0v[k] = WEq[(size_t)(unsigned)e * 16 + c];
    }
    int rkA[4], ekA[4], gsA[4];
    uint2 svA[4];
    #pragma unroll
    for (int s = 0; s < 4; ++s) {
        gsA[s] = __shfl(e1, 4 * s + qq);
        const int pk = adjP[(size_t)(unsigned)gsA[s] * KN + c];
        rkA[s] = pk & 31;
        ekA[s] = pk >> 5;
        svA[s] = WEq[(size_t)(unsigned)gsA[s] * 16 + c];
    }

    // ---- dot(u, rel_r) ----
    float acc;
    {
        float a0 = 0.f, a1 = 0.f;
        #pragma unroll
        for (int j = 0; j < 8; j += 2) {
            float4 a = rr[j],     b = ur[j];
            float4 cc = rr[j+1],  d = ur[j+1];
            a0 += a.x*b.x + a.y*b.y + a.z*b.z + a.w*b.w;
            a1 += cc.x*d.x + cc.y*d.y + cc.z*d.z + cc.w*d.w;
        }
        acc = a0 + a1;
        acc += __shfl_xor(acc, 1);
    }

    // softmax within 16-lane subgroups
    auto softmax16 = [&](float s) -> float {
        float mx = s;
        mx = fmaxf(mx, __shfl_xor(mx, 1));
        mx = fmaxf(mx, __shfl_xor(mx, 2));
        mx = fmaxf(mx, __shfl_xor(mx, 4));
        mx = fmaxf(mx, __shfl_xor(mx, 8));
        float e = __expf(s - mx);
        float ss = e;
        ss += __shfl_xor(ss, 1);
        ss += __shfl_xor(ss, 2);
        ss += __shfl_xor(ss, 4);
        ss += __shfl_xor(ss, 8);
        return e * frcp(ss);
    };

    // ---- issue slot 0's 64 rows as 32 DMA instructions (lane layout:
    // instr i covers rows idx=2i,2i+1; row idx = k*4+q; each lane reads
    // 4B at WEb[e(q,k)*128 + (lane&31)*4] -> LDS gbuf[idx*128 ...]) ----
    const int hi32 = lane >> 5;
    const int b32  = (lane & 31) << 2;
    #pragma unroll
    for (int i = 0; i < 32; ++i) {
        const int idx = 2 * i + hi32;
        const int q = idx & 3, k = idx >> 2;
        const int e = __shfl(ekA[0], q * 16 + k);
        gload_lds4((const char*)WEb + (((size_t)(unsigned)e) << 7) + b32,
                   (char*)gbuf + i * 256);
    }

    // ---- softmaxes + hop-0 consume run UNDER slot 0's DMA flight ----
    float wA[4];
    #pragma unroll
    for (int s = 0; s < 4; ++s) wA[s] = softmax16(__shfl(acc, rkA[s] << 1));
    const float w0 = softmax16(__shfl(acc, rk0 << 1));

    float hx = 0.f, hy = 0.f, hz = 0.f, hw = 0.f;
    #pragma unroll
    for (int k = 0; k < 4; ++k) {
        const float w = __shfl(w0, qq * 4 + k);
        hx += w * bflo(h0v[k].x);
        hy += w * bfhi(h0v[k].x);
        hz += w * bflo(h0v[k].y);
        hw += w * bfhi(h0v[k].y);
    }
    hx += __shfl_xor(hx, 16); hy += __shfl_xor(hy, 16);
    hz += __shfl_xor(hz, 16); hw += __shfl_xor(hw, 16);
    hx += __shfl_xor(hx, 32); hy += __shfl_xor(hy, 32);
    hz += __shfl_xor(hz, 32); hw += __shfl_xor(hw, 32);
    hx += bflo(itemv.x) + b4.x;
    hy += bfhi(itemv.x) + b4.y;
    hz += bflo(itemv.y) + b4.z;
    hw += bfhi(itemv.y) + b4.w;
    const float e0x = fmaxf(hx, 0.f), e0y = fmaxf(hy, 0.f);
    const float e0z = fmaxf(hz, 0.f), e0w = fmaxf(hw, 0.f);

    // ---- per-slot: wait DMA, consume from LDS, issue next slot ----
    #pragma unroll
    for (int s = 0; s < 4; ++s) {
        asm volatile("s_waitcnt vmcnt(0)" ::: "memory");
        __builtin_amdgcn_sched_barrier(0);

        float ax = b4.x + bflo(svA[s].x);
        float ay = b4.y + bfhi(svA[s].x);
        float az = b4.z + bflo(svA[s].y);
        float aw = b4.w + bfhi(svA[s].y);
        #pragma unroll
        for (int k = 0; k < KN; ++k) {
            const float w = __shfl(wA[s], qq * 16 + k);
            const uint2 v = gbuf[(k * 4 + qq) * 16 + c];
            ax += w * bflo(v.x);
            ay += w * bfhi(v.x);
            az += w * bflo(v.y);
            aw += w * bfhi(v.y);
        }

        // issue next slot's DMA before storing ev1 (overlap next latency)
        if (s < 3) {
            asm volatile("" ::: "memory");   // all gbuf reads above complete in-order (lgkm)
            asm volatile("s_waitcnt lgkmcnt(0)" ::: "memory");  // reads done before overwrite
            __builtin_amdgcn_sched_barrier(0);
            #pragma unroll
            for (int i = 0; i < 32; ++i) {
                const int idx = 2 * i + hi32;
                const int q = idx & 3, k = idx >> 2;
                const int e = __shfl(ekA[s + 1], q * 16 + k);
                gload_lds4((const char*)WEb + (((size_t)(unsigned)e) << 7) + b32,
                           (char*)gbuf + i * 256);
            }
        }

        *(float4*)&ev1[(4 * s + qq) * DIM + c4] =
            make_float4(fmaxf(ax, 0.f), fmaxf(ay, 0.f), fmaxf(az, 0.f), fmaxf(aw, 0.f));
    }

    // ---- layer 1 aggregate: x1 = e0 + sum_k w0_k * ev1_k ----
    asm volatile("s_waitcnt lgkmcnt(0)" ::: "memory");  // ev1 writes done (wave-local)
    float sx = 0.f, sy = 0.f, sz = 0.f, sw = 0.f;
    #pragma unroll
    for (int k = 0; k < 4; ++k) {
        const int   kg = qq * 4 + k;
        const float w  = __shfl(w0, kg);
        float4 ev = *(const float4*)&ev1[kg * DIM + c4];
        sx += w * ev.x;
        sy += w * ev.y;
        sz += w * ev.z;
        sw += w * ev.w;
    }
    sx += __shfl_xor(sx, 16); sy += __shfl_xor(sy, 16);
    sz += __shfl_xor(sz, 16); sw += __shfl_xor(sw, 16);
    sx += __shfl_xor(sx, 32); sy += __shfl_xor(sy, 32);
    sz += __shfl_xor(sz, 32); sw += __shfl_xor(sw, 32);

    // ---- the ONE real matvec: h1 = W x1 + b ----
    asm volatile("s_waitcnt lgkmcnt(0)" ::: "memory");
    if (qq == 0)
        *(float4*)&xb[c4] = make_float4(e0x + sx, e0y + sy, e0z + sz, e0w + sw);
    asm volatile("s_waitcnt lgkmcnt(0)" ::: "memory");
    float h0 = bl, h1 = 0.f, h2 = 0.f, h3 = 0.f;
    {
        const float4* Wl  = (const float4*)(W + lane * DIM);
        const float4* xv4 = (const float4*)xb;
        #pragma unroll
        for (int j = 0; j < 16; j += 4) {
            float4 w0v = Wl[j],   x0v = xv4[j];
            float4 w1v = Wl[j+1], x1v = xv4[j+1];
            float4 w2v = Wl[j+2], x2v = xv4[j+2];
            float4 w3v = Wl[j+3], x3v = xv4[j+3];
            h0 += w0v.x*x0v.x + w0v.y*x0v.y + w0v.z*x0v.z + w0v.w*x0v.w;
            h1 += w1v.x*x1v.x + w1v.y*x1v.y + w1v.z*x1v.z + w1v.w*x1v.w;
            h2 += w2v.x*x2v.x + w2v.y*x2v.y + w2v.z*x2v.z + w2v.w*x2v.w;
            h3 += w3v.x*x3v.x + w3v.y*x3v.y + w3v.z*x3v.z + w3v.w*x3v.w;
        }
    }
    const float itemf = tanhf((h0 + h1) + (h2 + h3));

    float d = user_emb[(size_t)user * DIM + lane] * itemf;
    d += __shfl_xor(d, 1);
    d += __shfl_xor(d, 2);
    d += __shfl_xor(d, 4);
    d += __shfl_xor(d, 8);
    d += __shfl_xor(d, 16);
    d += __shfl_xor(d, 32);
    if (lane == 0) out[p] = 1.f / (1.f + expf(-d));
}

// ============================================================================
// Fallback (verified R5 kernel) in case ws_size < WE + adjP table size.
// ============================================================================
__global__ __launch_bounds__(256, 4) void kgcn_fallback(
    const int* __restrict__ pairs, const int* __restrict__ adj_entity,
    const int* __restrict__ adj_relation, const float* __restrict__ entity_emb,
    const float* __restrict__ relation_emb, const float* __restrict__ user_emb,
    const float* __restrict__ W, const float* __restrict__ bias,
    float* __restrict__ out, int nPairs)
{
    __shared__ float ev1_s[2][KN * DIM];
    __shared__ float xb_s[4][DIM];
    const int tid = threadIdx.x, wave = tid >> 6, lane = tid & 63;
    const int q = wave >> 1, half = wave & 1;
    int p = blockIdx.x * 2 + q;
    if (p >= nPairs) p = nPairs - 1;
    float* ev1 = ev1_s[q]; float* xb = xb_s[wave];
    const int user = pairs[2 * p + 0], item = pairs[2 * p + 1];
    const float bval = bias[lane];
    const float* emb_l = entity_emb + lane;
    const float4* W4 = (const float4*)(W + lane * DIM);
    int rk0 = 0, e1 = 0;
    if (lane < KN) {
        rk0 = adj_relation[(size_t)item * KN + lane];
        e1  = adj_entity[(size_t)item * KN + lane];
    }
    float acc;
    {
        const int r = lane >> 1, hlf = lane & 1;
        const float4* rel4 = (const float4*)(relation_emb + r * DIM + hlf * 32);
        const float4* u4 = (const float4*)(user_emb + (size_t)user * DIM + hlf * 32);
        float a0 = 0.f, a1 = 0.f;
        #pragma unroll
        for (int j = 0; j < 8; j += 2) {
            float4 a = rel4[j], b = u4[j], c = rel4[j+1], d = u4[j+1];
            a0 += a.x*b.x + a.y*b.y + a.z*b.z + a.w*b.w;
            a1 += c.x*d.x + c.y*d.y + c.z*d.z + c.w*d.w;
        }
        acc = a0 + a1; acc += __shfl_xor(acc, 1);
    }
    auto softmax16 = [&](float s) -> float {
        float mx = s;
        mx = fmaxf(mx, __shfl_xor(mx, 1)); mx = fmaxf(mx, __shfl_xor(mx, 2));
        mx = fmaxf(mx, __shfl_xor(mx, 4)); mx = fmaxf(mx, __shfl_xor(mx, 8));
        float e = __expf(s - mx);
        float ss = e;
        ss += __shfl_xor(ss, 1); ss += __shfl_xor(ss, 2);
        ss += __shfl_xor(ss, 4); ss += __shfl_xor(ss, 8);
        return e * frcp(ss);
    };
    auto matvec = [&](float xv) -> float {
        asm volatile("s_waitcnt lgkmcnt(0)" ::: "memory");
        xb[lane] = xv;
        asm volatile("s_waitcnt lgkmcnt(0)" ::: "memory");
        float h0 = bval, h1 = 0.f, h2 = 0.f, h3 = 0.f;
        const float4* xv4 = (const float4*)xb;
        #pragma unroll
        for (int j = 0; j < 16; j += 4) {
            float4 w0 = W4[j], x0 = xv4[j], w1 = W4[j+1], x1 = xv4[j+1];
            float4 w2 = W4[j+2], x2 = xv4[j+2], w3 = W4[j+3], x3 = xv4[j+3];
            h0 += w0.x*x0.x + w0.y*x0.y + w0.z*x0.z + w0.w*x0.w;
            h1 += w1.x*x1.x + w1.y*x1.y + w1.z*x1.z + w1.w*x1.w;
            h2 += w2.x*x2.x + w2.y*x2.y + w2.z*x2.z + w2.w*x2.w;
            h3 += w3.x*x3.x + w3.y*x3.y + w3.z*x3.z + w3.w*x3.w;
        }
        return (h0 + h1) + (h2 + h3);
    };
    auto gather = [&](int self, int ek, float w) -> float {
        float xa = emb_l[(size_t)(unsigned)self * DIM], xc = 0.f;
        #pragma unroll
        for (int k = 0; k < KN; k += 2) {
            const int e0i = __shfl(ek, k); const float f0 = __shfl(w, k);
            const int e1i = __shfl(ek, k + 1); const float f1 = __shfl(w, k + 1);
            xa += f0 * emb_l[(size_t)(unsigned)e0i * DIM];
            xc += f1 * emb_l[(size_t)(unsigned)e1i * DIM];
        }
        return xa + xc;
    };
    int rk_n = 0, ek_n = 0;
    {
        const int g0 = __shfl(e1, half * 8);
        if (lane < KN) {
            rk_n = adj_relation[(size_t)(unsigned)g0 * KN + lane];
            ek_n = adj_entity[(size_t)(unsigned)g0 * KN + lane];
        }
    }
    #pragma unroll 1
    for (int mi = 0; mi < 8; ++mi) {
        const int m = half * 8 + mi;
        const int g = __shfl(e1, m);
        const int rk = rk_n, ek = ek_n;
        if (mi + 1 < 8) {
            const int gn = __shfl(e1, m + 1);
            if (lane < KN) {
                rk_n = adj_relation[(size_t)(unsigned)gn * KN + lane];
                ek_n = adj_entity[(size_t)(unsigned)gn * KN + lane];
            }
        }
        const float w = softmax16(__shfl(acc, rk << 1));
        const float x = gather(g, ek, w);
        ev1[m * DIM + lane] = fmaxf(matvec(x), 0.f);
    }
    __syncthreads();
    if (half != 0) return;
    const float w0 = softmax16(__shfl(acc, rk0 << 1));
    const float x0 = gather(item, e1, w0);
    const float e0 = fmaxf(matvec(x0), 0.f);
    float xa = e0, xc = 0.f;
    #pragma unroll
    for (int k = 0; k < KN; k += 2) {
        xa += __shfl(w0, k) * ev1[k * DIM + lane];
        xc += __shfl(w0, k + 1) * ev1[(k + 1) * DIM + lane];
    }
    const float itemf = tanhf(matvec(xa + xc));
    float d = user_emb[(size_t)user * DIM + lane] * itemf;
    d += __shfl_xor(d, 1); d += __shfl_xor(d, 2); d += __shfl_xor(d, 4);
    d += __shfl_xor(d, 8); d += __shfl_xor(d, 16); d += __shfl_xor(d, 32);
    if (lane == 0) out[p] = 1.f / (1.f + expf(-d));
}

extern "C" void kernel_launch(void* const* d_in, const int* in_sizes, int n_in,
                              void* d_out, int out_size, void* d_ws, size_t ws_size,
                              hipStream_t stream) {
    const int*   pairs        = (const int*)d_in[0];
    const int*   adj_entity   = (const int*)d_in[1];
    const int*   adj_relation = (const int*)d_in[2];
    const float* entity_emb   = (const float*)d_in[3];
    const float* relation_emb = (const float*)d_in[4];
    const float* user_emb     = (const float*)d_in[5];
    const float* W            = (const float*)d_in[6];
    const float* b            = (const float*)d_in[7];
    float* out = (float*)d_out;

    const int nPairs = in_sizes[0] / 2;          // pairs is (B, 2)
    const int nEnt   = in_sizes[3] / DIM;        // entity count
    const size_t weBytes   = (size_t)in_sizes[3] * sizeof(unsigned short);
    const size_t weAligned = (weBytes + 255) & ~(size_t)255;
    const size_t adjBytes  = (size_t)nEnt * KN * sizeof(int);

    if (ws_size >= weAligned + adjBytes) {
        unsigned short* WEb = (unsigned short*)d_ws;
        int* adjP = (int*)((char*)d_ws + weAligned);
        const int nTiles = (nEnt + 15) >> 4;
        const int preBlocks = (nTiles + 7) / 8;   // 2 tiles/wave, 4 waves/block
        we_kernel_mfma<<<preBlocks, 256, 0, stream>>>(entity_emb, W,
                                                      adj_entity, adj_relation,
                                                      WEb, adjP, nEnt);
        const int mainBlocks = (nPairs + 3) / 4;  // 1 wave/pair
        kgcn_main<<<mainBlocks, 256, 0, stream>>>(pairs, adjP,
                                                  WEb, relation_emb, user_emb,
                                                  W, b, out, nPairs);
    } else {
        const int nBlocks = (nPairs + 1) / 2;
        kgcn_fallback<<<nBlocks, 256, 0, stream>>>(pairs, adj_entity, adj_relation,
                                                   entity_emb, relation_emb, user_emb,
                                                   W, b, out, nPairs);
    }
}

// Round 8
// 129.960 us; speedup vs baseline: 1.0675x; 1.0675x over previous
//
#include <hip/hip_runtime.h>
#include <hip/hip_bf16.h>
#include <math.h>

#define DIM  64
#define KN   16
#define NREL 32

__device__ __forceinline__ float frcp(float x) { return __builtin_amdgcn_rcpf(x); }

__device__ __forceinline__ unsigned short f2bf(float f) {
    unsigned u = __float_as_uint(f);
    u = (u + 0x7fffu + ((u >> 16) & 1u)) >> 16;   // RNE
    return (unsigned short)u;
}
// bf16 pair packed in a dword: low ushort = even dim, high ushort = odd dim
__device__ __forceinline__ float bflo(unsigned v) { return __uint_as_float(v << 16); }
__device__ __forceinline__ float bfhi(unsigned v) { return __uint_as_float(v & 0xffff0000u); }

typedef __attribute__((ext_vector_type(8))) short bfrag;   // 8 bf16 (4 VGPRs)
typedef __attribute__((ext_vector_type(4))) float f32x4;   // MFMA accumulator
typedef __attribute__((ext_vector_type(2))) float f32x2;   // fp8 cvt result

// ============================================================================
// Kernel 1 (R18): WE precompute as MFMA GEMM + adjacency packing + an fp8
// e4m3 copy of WE (64 B/row) for the hop-1 neighbor gathers (93% of the
// main kernel's gather bytes). bf16 table kept for item/hop-0/self rows.
// ============================================================================
__global__ __launch_bounds__(256, 2) void we_kernel_mfma(
    const float* __restrict__ entity_emb,
    const float* __restrict__ W,
    const int* __restrict__ adjE,
    const int* __restrict__ adjR,
    unsigned short* __restrict__ WEb,
    unsigned char* __restrict__ WE8,
    int* __restrict__ adjP,
    int nRows)
{
    const int tid  = threadIdx.x;
    const int wave = tid >> 6;
    const int lane = tid & 63;
    const int c = lane & 15;
    const int g = lane >> 4;

    // ---- pack adjacency: 8 entries per thread, int4 vectorized ----
    {
        const size_t nEntries = (size_t)nRows * KN;
        const size_t base = ((size_t)blockIdx.x * 256 + tid) * 8;
        if (base + 8 <= nEntries) {
            const int4* e4 = (const int4*)(adjE + base);
            const int4* r4 = (const int4*)(adjR + base);
            const int4 e0 = e4[0], e1v = e4[1];
            const int4 r0 = r4[0], r1v = r4[1];
            int4 p0, p1;
            p0.x = (e0.x << 5) | r0.x;  p0.y = (e0.y << 5) | r0.y;
            p0.z = (e0.z << 5) | r0.z;  p0.w = (e0.w << 5) | r0.w;
            p1.x = (e1v.x << 5) | r1v.x; p1.y = (e1v.y << 5) | r1v.y;
            p1.z = (e1v.z << 5) | r1v.z; p1.w = (e1v.w << 5) | r1v.w;
            ((int4*)(adjP + base))[0] = p0;
            ((int4*)(adjP + base))[1] = p1;
        } else if (base < nEntries) {
            for (size_t i = base; i < nEntries; ++i)
                adjP[i] = (adjE[i] << 5) | adjR[i];
        }
    }

    const int nTiles = (nRows + 15) >> 4;
    const int t0 = (blockIdx.x * 4 + wave) * 2;       // 2 tiles per wave
    if (t0 >= nTiles) return;

    bfrag a[4][2];
    #pragma unroll
    for (int m = 0; m < 4; ++m) {
        #pragma unroll
        for (int ks = 0; ks < 2; ++ks) {
            const float4* ws = (const float4*)(W + (size_t)(16 * m + c) * DIM + 8 * g + 32 * ks);
            const float4 w0 = ws[0], w1 = ws[1];
            a[m][ks][0] = (short)f2bf(w0.x); a[m][ks][1] = (short)f2bf(w0.y);
            a[m][ks][2] = (short)f2bf(w0.z); a[m][ks][3] = (short)f2bf(w0.w);
            a[m][ks][4] = (short)f2bf(w1.x); a[m][ks][5] = (short)f2bf(w1.y);
            a[m][ks][6] = (short)f2bf(w1.z); a[m][ks][7] = (short)f2bf(w1.w);
        }
    }

    float4 pe[2][4];
    #pragma unroll
    for (int j = 0; j < 2; ++j) {
        const int t = (t0 + j < nTiles) ? (t0 + j) : 0;
        int row = 16 * t + c;
        if (row >= nRows) row = nRows - 1;
        const float4* src = (const float4*)(entity_emb + (size_t)row * DIM + 8 * g);
        pe[j][0] = src[0];
        pe[j][1] = src[1];
        pe[j][2] = src[8];
        pe[j][3] = src[9];
    }

    #pragma unroll
    for (int j = 0; j < 2; ++j) {
        const int t = t0 + j;
        if (t >= nTiles) continue;

        bfrag b0, b1;
        b0[0] = (short)f2bf(pe[j][0].x); b0[1] = (short)f2bf(pe[j][0].y);
        b0[2] = (short)f2bf(pe[j][0].z); b0[3] = (short)f2bf(pe[j][0].w);
        b0[4] = (short)f2bf(pe[j][1].x); b0[5] = (short)f2bf(pe[j][1].y);
        b0[6] = (short)f2bf(pe[j][1].z); b0[7] = (short)f2bf(pe[j][1].w);
        b1[0] = (short)f2bf(pe[j][2].x); b1[1] = (short)f2bf(pe[j][2].y);
        b1[2] = (short)f2bf(pe[j][2].z); b1[3] = (short)f2bf(pe[j][2].w);
        b1[4] = (short)f2bf(pe[j][3].x); b1[5] = (short)f2bf(pe[j][3].y);
        b1[6] = (short)f2bf(pe[j][3].z); b1[7] = (short)f2bf(pe[j][3].w);

        f32x4 acc[4];
        #pragma unroll
        for (int m = 0; m < 4; ++m) {
            f32x4 z = {0.f, 0.f, 0.f, 0.f};
            z = __builtin_amdgcn_mfma_f32_16x16x32_bf16(a[m][0], b0, z, 0, 0, 0);
            z = __builtin_amdgcn_mfma_f32_16x16x32_bf16(a[m][1], b1, z, 0, 0, 0);
            acc[m] = z;
        }

        const int erow = 16 * t + c;
        if (erow < nRows) {
            #pragma unroll
            for (int m = 0; m < 4; ++m) {
                // bf16 row (item/hop-0/self path)
                const unsigned lo = (unsigned)f2bf(acc[m][0]) | ((unsigned)f2bf(acc[m][1]) << 16);
                const unsigned hi = (unsigned)f2bf(acc[m][2]) | ((unsigned)f2bf(acc[m][3]) << 16);
                *(uint2*)(WEb + (size_t)erow * DIM + 16 * m + 4 * g) = make_uint2(lo, hi);
                // fp8 e4m3 row (hop-1 neighbor path), 4 dims -> 1 dword
                int r8 = 0;
                r8 = __builtin_amdgcn_cvt_pk_fp8_f32(acc[m][0], acc[m][1], r8, false);
                r8 = __builtin_amdgcn_cvt_pk_fp8_f32(acc[m][2], acc[m][3], r8, true);
                *(unsigned*)(WE8 + (size_t)erow * DIM + 16 * m + 4 * g) = (unsigned)r8;
            }
        }
    }
}

// ============================================================================
// Kernel 2 (R18): R16/R14 verified structure (DMA reverted — R17 regressed
// 9us). Hop-1 neighbor gathers read the fp8 table (4 B/lane instead of
// 8 B/lane): halves the dominant byte stream AND shrinks the hot table to
// 6.4 MB for better per-XCD L2 retention. Decode: v_cvt_pk_f32_fp8 x2.
// ============================================================================
__global__ __launch_bounds__(256, 3) void kgcn_main(
    const int* __restrict__ pairs,
    const int* __restrict__ adjP,
    const unsigned short* __restrict__ WEb,
    const unsigned char* __restrict__ WE8,
    const float* __restrict__ relation_emb,
    const float* __restrict__ user_emb,
    const float* __restrict__ W,
    const float* __restrict__ bias,
    float* __restrict__ out,
    int nPairs)
{
    __shared__ float ev1_s[4][KN * DIM];  // per-wave layer-0 outputs
    __shared__ float xb_s[4][DIM];        // per-wave matvec broadcast buffer

    const int tid  = threadIdx.x;
    const int wave = tid >> 6;
    const int lane = tid & 63;
    const int p    = blockIdx.x * 4 + wave;
    if (p >= nPairs) return;              // no barriers -> safe early-out

    float* ev1 = ev1_s[wave];
    float* xb  = xb_s[wave];

    const int qq = lane >> 4;             // quarter-wave id (0..3)
    const int c  = lane & 15;             // column within a WE row
    const int c4 = c * 4;                 // first owned dim

    const int user = pairs[2 * p + 0];
    const int item = pairs[2 * p + 1];

    const float4 b4 = *(const float4*)(bias + c4);
    const uint2* WEq  = (const uint2*)WEb;     // bf16 row = 16 uint2
    const unsigned* W8q = (const unsigned*)WE8; // fp8 row = 16 uint

    // ---- chase root: item packed adjacency row (single load) ----
    int rk0 = 0, e1 = 0;
    if (lane < KN) {
        const int pk0 = adjP[(size_t)item * KN + lane];
        rk0 = pk0 & 31;
        e1  = pk0 >> 5;
    }

    // ---- independent: user/relation rows into regs (fly during e1 wait) ----
    float4 rr[8], ur[8];
    {
        const int r = lane >> 1, hlf = lane & 1;
        const float4* rel4 = (const float4*)(relation_emb + r * DIM + hlf * 32);
        const float4* u4   = (const float4*)(user_emb + (size_t)user * DIM + hlf * 32);
        #pragma unroll
        for (int j = 0; j < 8; ++j) { rr[j] = rel4[j]; ur[j] = u4[j]; }
    }

    // ---- e1 arrival gates: hop-0 rows + slot adjacency (issue ASAP) ----
    const uint2 itemv = WEq[(size_t)item * 16 + c];
    uint2 h0v[4];
    #pragma unroll
    for (int k = 0; k < 4; ++k) {
        const int e = __shfl(e1, qq * 4 + k);
        h0v[k] = WEq[(size_t)(unsigned)e * 16 + c];
    }
    int rkA[4], ekA[4], gsA[4];
    #pragma unroll
    for (int s = 0; s < 4; ++s) {
        gsA[s] = __shfl(e1, 4 * s + qq);
        const int pk = adjP[(size_t)(unsigned)gsA[s] * KN + c];
        rkA[s] = pk & 31;
        ekA[s] = pk >> 5;
    }

    // ---- dot(u, rel_r): consume the reg-staged rows (adjacency in flight) ----
    float acc;
    {
        float a0 = 0.f, a1 = 0.f;
        #pragma unroll
        for (int j = 0; j < 8; j += 2) {
            float4 a = rr[j],     b = ur[j];
            float4 cc = rr[j+1],  d = ur[j+1];
            a0 += a.x*b.x + a.y*b.y + a.z*b.z + a.w*b.w;
            a1 += cc.x*d.x + cc.y*d.y + cc.z*d.z + cc.w*d.w;
        }
        acc = a0 + a1;
        acc += __shfl_xor(acc, 1);
    }

    // ---- ISSUE hop-1 gathers for slots 0..2 (fp8: 4 B/lane) + self rows ----
    uint2 svA[4];
    unsigned nvA[3][KN];
    #pragma unroll
    for (int s = 0; s < 3; ++s) {
        svA[s] = WEq[(size_t)(unsigned)gsA[s] * 16 + c];
        #pragma unroll
        for (int k = 0; k < KN; ++k) {
            const int e = __shfl(ekA[s], qq * 16 + k);
            nvA[s][k] = W8q[(size_t)(unsigned)e * 16 + c];
        }
    }
    svA[3] = WEq[(size_t)(unsigned)gsA[3] * 16 + c];

    // softmax within 16-lane subgroups (4 independent groups per call)
    auto softmax16 = [&](float s) -> float {
        float mx = s;
        mx = fmaxf(mx, __shfl_xor(mx, 1));
        mx = fmaxf(mx, __shfl_xor(mx, 2));
        mx = fmaxf(mx, __shfl_xor(mx, 4));
        mx = fmaxf(mx, __shfl_xor(mx, 8));
        float e = __expf(s - mx);
        float ss = e;
        ss += __shfl_xor(ss, 1);
        ss += __shfl_xor(ss, 2);
        ss += __shfl_xor(ss, 4);
        ss += __shfl_xor(ss, 8);
        return e * frcp(ss);
    };

    // ---- softmaxes run UNDER the gather flight ----
    float wA[4];
    #pragma unroll
    for (int s = 0; s < 4; ++s) wA[s] = softmax16(__shfl(acc, rkA[s] << 1));
    const float w0 = softmax16(__shfl(acc, rk0 << 1));

    // ---- consume slot 0, then issue slot 3's neighbors ----
    {
        float ax = b4.x + bflo(svA[0].x);
        float ay = b4.y + bfhi(svA[0].x);
        float az = b4.z + bflo(svA[0].y);
        float aw = b4.w + bfhi(svA[0].y);
        #pragma unroll
        for (int k = 0; k < KN; ++k) {
            const float w = __shfl(wA[0], qq * 16 + k);
            const f32x2 lo = __builtin_amdgcn_cvt_pk_f32_fp8(nvA[0][k], false);
            const f32x2 hi = __builtin_amdgcn_cvt_pk_f32_fp8(nvA[0][k], true);
            ax += w * lo.x;
            ay += w * lo.y;
            az += w * hi.x;
            aw += w * hi.y;
        }
        *(float4*)&ev1[qq * DIM + c4] =
            make_float4(fmaxf(ax, 0.f), fmaxf(ay, 0.f), fmaxf(az, 0.f), fmaxf(aw, 0.f));
    }
    unsigned nv3[KN];
    #pragma unroll
    for (int k = 0; k < KN; ++k) {
        const int e = __shfl(ekA[3], qq * 16 + k);
        nv3[k] = W8q[(size_t)(unsigned)e * 16 + c];
    }
    #pragma unroll
    for (int s = 1; s < 3; ++s) {
        float ax = b4.x + bflo(svA[s].x);
        float ay = b4.y + bfhi(svA[s].x);
        float az = b4.z + bflo(svA[s].y);
        float aw = b4.w + bfhi(svA[s].y);
        #pragma unroll
        for (int k = 0; k < KN; ++k) {
            const float w = __shfl(wA[s], qq * 16 + k);
            const f32x2 lo = __builtin_amdgcn_cvt_pk_f32_fp8(nvA[s][k], false);
            const f32x2 hi = __builtin_amdgcn_cvt_pk_f32_fp8(nvA[s][k], true);
            ax += w * lo.x;
            ay += w * lo.y;
            az += w * hi.x;
            aw += w * hi.y;
        }
        *(float4*)&ev1[(4 * s + qq) * DIM + c4] =
            make_float4(fmaxf(ax, 0.f), fmaxf(ay, 0.f), fmaxf(az, 0.f), fmaxf(aw, 0.f));
    }
    {
        float ax = b4.x + bflo(svA[3].x);
        float ay = b4.y + bfhi(svA[3].x);
        float az = b4.z + bflo(svA[3].y);
        float aw = b4.w + bfhi(svA[3].y);
        #pragma unroll
        for (int k = 0; k < KN; ++k) {
            const float w = __shfl(wA[3], qq * 16 + k);
            const f32x2 lo = __builtin_amdgcn_cvt_pk_f32_fp8(nv3[k], false);
            const f32x2 hi = __builtin_amdgcn_cvt_pk_f32_fp8(nv3[k], true);
            ax += w * lo.x;
            ay += w * lo.y;
            az += w * hi.x;
            aw += w * hi.y;
        }
        *(float4*)&ev1[(12 + qq) * DIM + c4] =
            make_float4(fmaxf(ax, 0.f), fmaxf(ay, 0.f), fmaxf(az, 0.f), fmaxf(aw, 0.f));
    }

    // ---- hop 0, layer 0: accumulate the preloaded bf16 rows ----
    float ax = 0.f, ay = 0.f, az = 0.f, aw = 0.f;
    #pragma unroll
    for (int k = 0; k < 4; ++k) {
        const float w = __shfl(w0, qq * 4 + k);
        ax += w * bflo(h0v[k].x);
        ay += w * bfhi(h0v[k].x);
        az += w * bflo(h0v[k].y);
        aw += w * bfhi(h0v[k].y);
    }
    ax += __shfl_xor(ax, 16); ay += __shfl_xor(ay, 16);
    az += __shfl_xor(az, 16); aw += __shfl_xor(aw, 16);
    ax += __shfl_xor(ax, 32); ay += __shfl_xor(ay, 32);
    az += __shfl_xor(az, 32); aw += __shfl_xor(aw, 32);
    ax += bflo(itemv.x) + b4.x;
    ay += bfhi(itemv.x) + b4.y;
    az += bflo(itemv.y) + b4.z;
    aw += bfhi(itemv.y) + b4.w;
    const float e0x = fmaxf(ax, 0.f), e0y = fmaxf(ay, 0.f);
    const float e0z = fmaxf(az, 0.f), e0w = fmaxf(aw, 0.f);

    // ---- layer 1 aggregate: x1 = e0 + sum_k w0_k * ev1_k (quarter-split)
    asm volatile("s_waitcnt lgkmcnt(0)" ::: "memory");  // ev1 writes done (wave-local)
    float sx = 0.f, sy = 0.f, sz = 0.f, sw = 0.f;
    #pragma unroll
    for (int k = 0; k < 4; ++k) {
        const int   kg = qq * 4 + k;
        const float w  = __shfl(w0, kg);
        float4 ev = *(const float4*)&ev1[kg * DIM + c4];
        sx += w * ev.x;
        sy += w * ev.y;
        sz += w * ev.z;
        sw += w * ev.w;
    }
    sx += __shfl_xor(sx, 16); sy += __shfl_xor(sy, 16);
    sz += __shfl_xor(sz, 16); sw += __shfl_xor(sw, 16);
    sx += __shfl_xor(sx, 32); sy += __shfl_xor(sy, 32);
    sz += __shfl_xor(sz, 32); sw += __shfl_xor(sw, 32);

    // ---- the ONE real matvec: h1 = W x1 + b, via LDS broadcast ----
    asm volatile("s_waitcnt lgkmcnt(0)" ::: "memory");
    if (qq == 0)
        *(float4*)&xb[c4] = make_float4(e0x + sx, e0y + sy, e0z + sz, e0w + sw);
    asm volatile("s_waitcnt lgkmcnt(0)" ::: "memory");
    float h0 = bias[lane], h1 = 0.f, h2 = 0.f, h3 = 0.f;
    {
        const float4* Wl  = (const float4*)(W + lane * DIM);
        const float4* xv4 = (const float4*)xb;
        #pragma unroll
        for (int j = 0; j < 16; j += 4) {
            float4 w0v = Wl[j],   x0v = xv4[j];
            float4 w1v = Wl[j+1], x1v = xv4[j+1];
            float4 w2v = Wl[j+2], x2v = xv4[j+2];
            float4 w3v = Wl[j+3], x3v = xv4[j+3];
            h0 += w0v.x*x0v.x + w0v.y*x0v.y + w0v.z*x0v.z + w0v.w*x0v.w;
            h1 += w1v.x*x1v.x + w1v.y*x1v.y + w1v.z*x1v.z + w1v.w*x1v.w;
            h2 += w2v.x*x2v.x + w2v.y*x2v.y + w2v.z*x2v.z + w2v.w*x2v.w;
            h3 += w3v.x*x3v.x + w3v.y*x3v.y + w3v.z*x3v.z + w3v.w*x3v.w;
        }
    }
    const float itemf = tanhf((h0 + h1) + (h2 + h3));

    float d = user_emb[(size_t)user * DIM + lane] * itemf;
    d += __shfl_xor(d, 1);
    d += __shfl_xor(d, 2);
    d += __shfl_xor(d, 4);
    d += __shfl_xor(d, 8);
    d += __shfl_xor(d, 16);
    d += __shfl_xor(d, 32);
    if (lane == 0) out[p] = 1.f / (1.f + expf(-d));
}

// ============================================================================
// Fallback (verified R5 kernel) in case ws_size < table sizes.
// ============================================================================
__global__ __launch_bounds__(256, 4) void kgcn_fallback(
    const int* __restrict__ pairs, const int* __restrict__ adj_entity,
    const int* __restrict__ adj_relation, const float* __restrict__ entity_emb,
    const float* __restrict__ relation_emb, const float* __restrict__ user_emb,
    const float* __restrict__ W, const float* __restrict__ bias,
    float* __restrict__ out, int nPairs)
{
    __shared__ float ev1_s[2][KN * DIM];
    __shared__ float xb_s[4][DIM];
    const int tid = threadIdx.x, wave = tid >> 6, lane = tid & 63;
    const int q = wave >> 1, half = wave & 1;
    int p = blockIdx.x * 2 + q;
    if (p >= nPairs) p = nPairs - 1;
    float* ev1 = ev1_s[q]; float* xb = xb_s[wave];
    const int user = pairs[2 * p + 0], item = pairs[2 * p + 1];
    const float bval = bias[lane];
    const float* emb_l = entity_emb + lane;
    const float4* W4 = (const float4*)(W + lane * DIM);
    int rk0 = 0, e1 = 0;
    if (lane < KN) {
        rk0 = adj_relation[(size_t)item * KN + lane];
        e1  = adj_entity[(size_t)item * KN + lane];
    }
    float acc;
    {
        const int r = lane >> 1, hlf = lane & 1;
        const float4* rel4 = (const float4*)(relation_emb + r * DIM + hlf * 32);
        const float4* u4 = (const float4*)(user_emb + (size_t)user * DIM + hlf * 32);
        float a0 = 0.f, a1 = 0.f;
        #pragma unroll
        for (int j = 0; j < 8; j += 2) {
            float4 a = rel4[j], b = u4[j], c = rel4[j+1], d = u4[j+1];
            a0 += a.x*b.x + a.y*b.y + a.z*b.z + a.w*b.w;
            a1 += c.x*d.x + c.y*d.y + c.z*d.z + c.w*d.w;
        }
        acc = a0 + a1; acc += __shfl_xor(acc, 1);
    }
    auto softmax16 = [&](float s) -> float {
        float mx = s;
        mx = fmaxf(mx, __shfl_xor(mx, 1)); mx = fmaxf(mx, __shfl_xor(mx, 2));
        mx = fmaxf(mx, __shfl_xor(mx, 4)); mx = fmaxf(mx, __shfl_xor(mx, 8));
        float e = __expf(s - mx);
        float ss = e;
        ss += __shfl_xor(ss, 1); ss += __shfl_xor(ss, 2);
        ss += __shfl_xor(ss, 4); ss += __shfl_xor(ss, 8);
        return e * frcp(ss);
    };
    auto matvec = [&](float xv) -> float {
        asm volatile("s_waitcnt lgkmcnt(0)" ::: "memory");
        xb[lane] = xv;
        asm volatile("s_waitcnt lgkmcnt(0)" ::: "memory");
        float h0 = bval, h1 = 0.f, h2 = 0.f, h3 = 0.f;
        const float4* xv4 = (const float4*)xb;
        #pragma unroll
        for (int j = 0; j < 16; j += 4) {
            float4 w0 = W4[j], x0 = xv4[j], w1 = W4[j+1], x1 = xv4[j+1];
            float4 w2 = W4[j+2], x2 = xv4[j+2], w3 = W4[j+3], x3 = xv4[j+3];
            h0 += w0.x*x0.x + w0.y*x0.y + w0.z*x0.z + w0.w*x0.w;
            h1 += w1.x*x1.x + w1.y*x1.y + w1.z*x1.z + w1.w*x1.w;
            h2 += w2.x*x2.x + w2.y*x2.y + w2.z*x2.z + w2.w*x2.w;
            h3 += w3.x*x3.x + w3.y*x3.y + w3.z*x3.z + w3.w*x3.w;
        }
        return (h0 + h1) + (h2 + h3);
    };
    auto gather = [&](int self, int ek, float w) -> float {
        float xa = emb_l[(size_t)(unsigned)self * DIM], xc = 0.f;
        #pragma unroll
        for (int k = 0; k < KN; k += 2) {
            const int e0i = __shfl(ek, k); const float f0 = __shfl(w, k);
            const int e1i = __shfl(ek, k + 1); const float f1 = __shfl(w, k + 1);
            xa += f0 * emb_l[(size_t)(unsigned)e0i * DIM];
            xc += f1 * emb_l[(size_t)(unsigned)e1i * DIM];
        }
        return xa + xc;
    };
    int rk_n = 0, ek_n = 0;
    {
        const int g0 = __shfl(e1, half * 8);
        if (lane < KN) {
            rk_n = adj_relation[(size_t)(unsigned)g0 * KN + lane];
            ek_n = adj_entity[(size_t)(unsigned)g0 * KN + lane];
        }
    }
    #pragma unroll 1
    for (int mi = 0; mi < 8; ++mi) {
        const int m = half * 8 + mi;
        const int g = __shfl(e1, m);
        const int rk = rk_n, ek = ek_n;
        if (mi + 1 < 8) {
            const int gn = __shfl(e1, m + 1);
            if (lane < KN) {
                rk_n = adj_relation[(size_t)(unsigned)gn * KN + lane];
                ek_n = adj_entity[(size_t)(unsigned)gn * KN + lane];
            }
        }
        const float w = softmax16(__shfl(acc, rk << 1));
        const float x = gather(g, ek, w);
        ev1[m * DIM + lane] = fmaxf(matvec(x), 0.f);
    }
    __syncthreads();
    if (half != 0) return;
    const float w0 = softmax16(__shfl(acc, rk0 << 1));
    const float x0 = gather(item, e1, w0);
    const float e0 = fmaxf(matvec(x0), 0.f);
    float xa = e0, xc = 0.f;
    #pragma unroll
    for (int k = 0; k < KN; k += 2) {
        xa += __shfl(w0, k) * ev1[k * DIM + lane];
        xc += __shfl(w0, k + 1) * ev1[(k + 1) * DIM + lane];
    }
    const float itemf = tanhf(matvec(xa + xc));
    float d = user_emb[(size_t)user * DIM + lane] * itemf;
    d += __shfl_xor(d, 1); d += __shfl_xor(d, 2); d += __shfl_xor(d, 4);
    d += __shfl_xor(d, 8); d += __shfl_xor(d, 16); d += __shfl_xor(d, 32);
    if (lane == 0) out[p] = 1.f / (1.f + expf(-d));
}

extern "C" void kernel_launch(void* const* d_in, const int* in_sizes, int n_in,
                              void* d_out, int out_size, void* d_ws, size_t ws_size,
                              hipStream_t stream) {
    const int*   pairs        = (const int*)d_in[0];
    const int*   adj_entity   = (const int*)d_in[1];
    const int*   adj_relation = (const int*)d_in[2];
    const float* entity_emb   = (const float*)d_in[3];
    const float* relation_emb = (const float*)d_in[4];
    const float* user_emb     = (const float*)d_in[5];
    const float* W            = (const float*)d_in[6];
    const float* b            = (const float*)d_in[7];
    float* out = (float*)d_out;

    const int nPairs = in_sizes[0] / 2;          // pairs is (B, 2)
    const int nEnt   = in_sizes[3] / DIM;        // entity count
    const size_t weBytes   = (size_t)in_sizes[3] * sizeof(unsigned short);
    const size_t weAligned = (weBytes + 255) & ~(size_t)255;
    const size_t w8Bytes   = (size_t)in_sizes[3] * sizeof(unsigned char);
    const size_t w8Aligned = (w8Bytes + 255) & ~(size_t)255;
    const size_t adjBytes  = (size_t)nEnt * KN * sizeof(int);

    if (ws_size >= weAligned + w8Aligned + adjBytes) {
        unsigned short* WEb = (unsigned short*)d_ws;
        unsigned char*  WE8 = (unsigned char*)((char*)d_ws + weAligned);
        int* adjP = (int*)((char*)d_ws + weAligned + w8Aligned);
        const int nTiles = (nEnt + 15) >> 4;
        const int preBlocks = (nTiles + 7) / 8;   // 2 tiles/wave, 4 waves/block
        we_kernel_mfma<<<preBlocks, 256, 0, stream>>>(entity_emb, W,
                                                      adj_entity, adj_relation,
                                                      WEb, WE8, adjP, nEnt);
        const int mainBlocks = (nPairs + 3) / 4;  // 1 wave/pair
        kgcn_main<<<mainBlocks, 256, 0, stream>>>(pairs, adjP,
                                                  WEb, WE8, relation_emb, user_emb,
                                                  W, b, out, nPairs);
    } else {
        const int nBlocks = (nPairs + 1) / 2;
        kgcn_fallback<<<nBlocks, 256, 0, stream>>>(pairs, adj_entity, adj_relation,
                                                   entity_emb, relation_emb, user_emb,
                                                   W, b, out, nPairs);
    }
}

// Round 9
// 126.432 us; speedup vs baseline: 1.0973x; 1.0279x over previous
//
#include <hip/hip_runtime.h>
#include <hip/hip_bf16.h>
#include <math.h>

#define DIM  64
#define KN   16
#define NREL 32
#define S8   0.00390625f   // 2^-8: undo the x256 storage scale of WE8

__device__ __forceinline__ float frcp(float x) { return __builtin_amdgcn_rcpf(x); }

__device__ __forceinline__ unsigned short f2bf(float f) {
    unsigned u = __float_as_uint(f);
    u = (u + 0x7fffu + ((u >> 16) & 1u)) >> 16;   // RNE
    return (unsigned short)u;
}

typedef __attribute__((ext_vector_type(8))) short bfrag;   // 8 bf16 (4 VGPRs)
typedef __attribute__((ext_vector_type(4))) float f32x4;   // MFMA accumulator
typedef __attribute__((ext_vector_type(2))) float f32x2;   // fp8 cvt result

// ============================================================================
// Kernel 1 (R19): WE precompute as MFMA GEMM -> fp8 e4m3 ONLY, stored x256
// (WE elements ~1e-3..1e-1 land in e4m3's subnormal zone unscaled; x256
// moves them to full-mantissa normal range). bf16 table dropped entirely:
// hot set = WE8 6.4MB + adjP 6.4MB = 12.8MB, targeting per-XCD L2 hit rate
// (the line-fetch count into L2 is the measured bottleneck).
// ============================================================================
__global__ __launch_bounds__(256, 2) void we_kernel_mfma(
    const float* __restrict__ entity_emb,
    const float* __restrict__ W,
    const int* __restrict__ adjE,
    const int* __restrict__ adjR,
    unsigned char* __restrict__ WE8,
    int* __restrict__ adjP,
    int nRows)
{
    const int tid  = threadIdx.x;
    const int wave = tid >> 6;
    const int lane = tid & 63;
    const int c = lane & 15;
    const int g = lane >> 4;

    // ---- pack adjacency: 8 entries per thread, int4 vectorized ----
    {
        const size_t nEntries = (size_t)nRows * KN;
        const size_t base = ((size_t)blockIdx.x * 256 + tid) * 8;
        if (base + 8 <= nEntries) {
            const int4* e4 = (const int4*)(adjE + base);
            const int4* r4 = (const int4*)(adjR + base);
            const int4 e0 = e4[0], e1v = e4[1];
            const int4 r0 = r4[0], r1v = r4[1];
            int4 p0, p1;
            p0.x = (e0.x << 5) | r0.x;  p0.y = (e0.y << 5) | r0.y;
            p0.z = (e0.z << 5) | r0.z;  p0.w = (e0.w << 5) | r0.w;
            p1.x = (e1v.x << 5) | r1v.x; p1.y = (e1v.y << 5) | r1v.y;
            p1.z = (e1v.z << 5) | r1v.z; p1.w = (e1v.w << 5) | r1v.w;
            ((int4*)(adjP + base))[0] = p0;
            ((int4*)(adjP + base))[1] = p1;
        } else if (base < nEntries) {
            for (size_t i = base; i < nEntries; ++i)
                adjP[i] = (adjE[i] << 5) | adjR[i];
        }
    }

    const int nTiles = (nRows + 15) >> 4;
    const int t0 = (blockIdx.x * 4 + wave) * 2;       // 2 tiles per wave
    if (t0 >= nTiles) return;

    bfrag a[4][2];
    #pragma unroll
    for (int m = 0; m < 4; ++m) {
        #pragma unroll
        for (int ks = 0; ks < 2; ++ks) {
            const float4* ws = (const float4*)(W + (size_t)(16 * m + c) * DIM + 8 * g + 32 * ks);
            const float4 w0 = ws[0], w1 = ws[1];
            a[m][ks][0] = (short)f2bf(w0.x); a[m][ks][1] = (short)f2bf(w0.y);
            a[m][ks][2] = (short)f2bf(w0.z); a[m][ks][3] = (short)f2bf(w0.w);
            a[m][ks][4] = (short)f2bf(w1.x); a[m][ks][5] = (short)f2bf(w1.y);
            a[m][ks][6] = (short)f2bf(w1.z); a[m][ks][7] = (short)f2bf(w1.w);
        }
    }

    float4 pe[2][4];
    #pragma unroll
    for (int j = 0; j < 2; ++j) {
        const int t = (t0 + j < nTiles) ? (t0 + j) : 0;
        int row = 16 * t + c;
        if (row >= nRows) row = nRows - 1;
        const float4* src = (const float4*)(entity_emb + (size_t)row * DIM + 8 * g);
        pe[j][0] = src[0];
        pe[j][1] = src[1];
        pe[j][2] = src[8];
        pe[j][3] = src[9];
    }

    #pragma unroll
    for (int j = 0; j < 2; ++j) {
        const int t = t0 + j;
        if (t >= nTiles) continue;

        bfrag b0, b1;
        b0[0] = (short)f2bf(pe[j][0].x); b0[1] = (short)f2bf(pe[j][0].y);
        b0[2] = (short)f2bf(pe[j][0].z); b0[3] = (short)f2bf(pe[j][0].w);
        b0[4] = (short)f2bf(pe[j][1].x); b0[5] = (short)f2bf(pe[j][1].y);
        b0[6] = (short)f2bf(pe[j][1].z); b0[7] = (short)f2bf(pe[j][1].w);
        b1[0] = (short)f2bf(pe[j][2].x); b1[1] = (short)f2bf(pe[j][2].y);
        b1[2] = (short)f2bf(pe[j][2].z); b1[3] = (short)f2bf(pe[j][2].w);
        b1[4] = (short)f2bf(pe[j][3].x); b1[5] = (short)f2bf(pe[j][3].y);
        b1[6] = (short)f2bf(pe[j][3].z); b1[7] = (short)f2bf(pe[j][3].w);

        f32x4 acc[4];
        #pragma unroll
        for (int m = 0; m < 4; ++m) {
            f32x4 z = {0.f, 0.f, 0.f, 0.f};
            z = __builtin_amdgcn_mfma_f32_16x16x32_bf16(a[m][0], b0, z, 0, 0, 0);
            z = __builtin_amdgcn_mfma_f32_16x16x32_bf16(a[m][1], b1, z, 0, 0, 0);
            acc[m] = z;
        }

        const int erow = 16 * t + c;
        if (erow < nRows) {
            #pragma unroll
            for (int m = 0; m < 4; ++m) {
                // fp8 e4m3 row, values x256 (into normal range), 4 dims/dword
                int r8 = 0;
                r8 = __builtin_amdgcn_cvt_pk_fp8_f32(acc[m][0] * 256.f, acc[m][1] * 256.f, r8, false);
                r8 = __builtin_amdgcn_cvt_pk_fp8_f32(acc[m][2] * 256.f, acc[m][3] * 256.f, r8, true);
                *(unsigned*)(WE8 + (size_t)erow * DIM + 16 * m + 4 * g) = (unsigned)r8;
            }
        }
    }
}

// ============================================================================
// Kernel 2 (R19): all WE reads from the 6.4MB scaled-fp8 table (64B rows).
// Hot set = 12.8MB (WE8 + adjP) vs 25.6MB before -> L2 hit-rate lever on
// the line-fetch bottleneck. Structure = verified R14/R16 batched form.
// launch_bounds(256,4): fp8 gather arrays (uint not uint2) cut VGPR ~48.
// ============================================================================
__global__ __launch_bounds__(256, 4) void kgcn_main(
    const int* __restrict__ pairs,
    const int* __restrict__ adjP,
    const unsigned char* __restrict__ WE8,
    const float* __restrict__ relation_emb,
    const float* __restrict__ user_emb,
    const float* __restrict__ W,
    const float* __restrict__ bias,
    float* __restrict__ out,
    int nPairs)
{
    __shared__ float ev1_s[4][KN * DIM];  // per-wave layer-0 outputs
    __shared__ float xb_s[4][DIM];        // per-wave matvec broadcast buffer

    const int tid  = threadIdx.x;
    const int wave = tid >> 6;
    const int lane = tid & 63;
    const int p    = blockIdx.x * 4 + wave;
    if (p >= nPairs) return;              // no barriers -> safe early-out

    float* ev1 = ev1_s[wave];
    float* xb  = xb_s[wave];

    const int qq = lane >> 4;             // quarter-wave id (0..3)
    const int c  = lane & 15;             // dword column within a WE8 row
    const int c4 = c * 4;                 // first owned dim

    const int user = pairs[2 * p + 0];
    const int item = pairs[2 * p + 1];

    const float4 b4 = *(const float4*)(bias + c4);
    const unsigned* W8q = (const unsigned*)WE8;   // fp8 row = 16 dwords (64B)

    // ---- chase root: item packed adjacency row (single load) ----
    int rk0 = 0, e1 = 0;
    if (lane < KN) {
        const int pk0 = adjP[(size_t)item * KN + lane];
        rk0 = pk0 & 31;
        e1  = pk0 >> 5;
    }

    // ---- independent: user/relation rows into regs (fly during e1 wait) ----
    float4 rr[8], ur[8];
    {
        const int r = lane >> 1, hlf = lane & 1;
        const float4* rel4 = (const float4*)(relation_emb + r * DIM + hlf * 32);
        const float4* u4   = (const float4*)(user_emb + (size_t)user * DIM + hlf * 32);
        #pragma unroll
        for (int j = 0; j < 8; ++j) { rr[j] = rel4[j]; ur[j] = u4[j]; }
    }

    // ---- e1 arrival gates: hop-0 rows + slot adjacency (issue ASAP) ----
    const unsigned itemv8 = W8q[(size_t)item * 16 + c];
    unsigned h0v8[4];
    #pragma unroll
    for (int k = 0; k < 4; ++k) {
        const int e = __shfl(e1, qq * 4 + k);
        h0v8[k] = W8q[(size_t)(unsigned)e * 16 + c];
    }
    int rkA[4], ekA[4], gsA[4];
    #pragma unroll
    for (int s = 0; s < 4; ++s) {
        gsA[s] = __shfl(e1, 4 * s + qq);
        const int pk = adjP[(size_t)(unsigned)gsA[s] * KN + c];
        rkA[s] = pk & 31;
        ekA[s] = pk >> 5;
    }

    // ---- dot(u, rel_r) ----
    float acc;
    {
        float a0 = 0.f, a1 = 0.f;
        #pragma unroll
        for (int j = 0; j < 8; j += 2) {
            float4 a = rr[j],     b = ur[j];
            float4 cc = rr[j+1],  d = ur[j+1];
            a0 += a.x*b.x + a.y*b.y + a.z*b.z + a.w*b.w;
            a1 += cc.x*d.x + cc.y*d.y + cc.z*d.z + cc.w*d.w;
        }
        acc = a0 + a1;
        acc += __shfl_xor(acc, 1);
    }

    // ---- ISSUE hop-1 gathers for slots 0..2 + self rows (4 B/lane) ----
    unsigned svA8[4];
    unsigned nvA[3][KN];
    #pragma unroll
    for (int s = 0; s < 3; ++s) {
        svA8[s] = W8q[(size_t)(unsigned)gsA[s] * 16 + c];
        #pragma unroll
        for (int k = 0; k < KN; ++k) {
            const int e = __shfl(ekA[s], qq * 16 + k);
            nvA[s][k] = W8q[(size_t)(unsigned)e * 16 + c];
        }
    }
    svA8[3] = W8q[(size_t)(unsigned)gsA[3] * 16 + c];

    // softmax within 16-lane subgroups (4 independent groups per call)
    auto softmax16 = [&](float s) -> float {
        float mx = s;
        mx = fmaxf(mx, __shfl_xor(mx, 1));
        mx = fmaxf(mx, __shfl_xor(mx, 2));
        mx = fmaxf(mx, __shfl_xor(mx, 4));
        mx = fmaxf(mx, __shfl_xor(mx, 8));
        float e = __expf(s - mx);
        float ss = e;
        ss += __shfl_xor(ss, 1);
        ss += __shfl_xor(ss, 2);
        ss += __shfl_xor(ss, 4);
        ss += __shfl_xor(ss, 8);
        return e * frcp(ss);
    };

    // ---- softmaxes run UNDER the gather flight ----
    float wA[4];
    #pragma unroll
    for (int s = 0; s < 4; ++s) wA[s] = softmax16(__shfl(acc, rkA[s] << 1)) * S8;
    const float w0 = softmax16(__shfl(acc, rk0 << 1));   // unscaled: also weights f32 ev1

    // ---- consume slot 0, then issue slot 3's neighbors ----
    {
        const f32x2 slo = __builtin_amdgcn_cvt_pk_f32_fp8(svA8[0], false);
        const f32x2 shi = __builtin_amdgcn_cvt_pk_f32_fp8(svA8[0], true);
        float ax = b4.x + S8 * slo.x;
        float ay = b4.y + S8 * slo.y;
        float az = b4.z + S8 * shi.x;
        float aw = b4.w + S8 * shi.y;
        #pragma unroll
        for (int k = 0; k < KN; ++k) {
            const float w = __shfl(wA[0], qq * 16 + k);
            const f32x2 lo = __builtin_amdgcn_cvt_pk_f32_fp8(nvA[0][k], false);
            const f32x2 hi = __builtin_amdgcn_cvt_pk_f32_fp8(nvA[0][k], true);
            ax += w * lo.x;
            ay += w * lo.y;
            az += w * hi.x;
            aw += w * hi.y;
        }
        *(float4*)&ev1[qq * DIM + c4] =
            make_float4(fmaxf(ax, 0.f), fmaxf(ay, 0.f), fmaxf(az, 0.f), fmaxf(aw, 0.f));
    }
    unsigned nv3[KN];
    #pragma unroll
    for (int k = 0; k < KN; ++k) {
        const int e = __shfl(ekA[3], qq * 16 + k);
        nv3[k] = W8q[(size_t)(unsigned)e * 16 + c];
    }
    #pragma unroll
    for (int s = 1; s < 3; ++s) {
        const f32x2 slo = __builtin_amdgcn_cvt_pk_f32_fp8(svA8[s], false);
        const f32x2 shi = __builtin_amdgcn_cvt_pk_f32_fp8(svA8[s], true);
        float ax = b4.x + S8 * slo.x;
        float ay = b4.y + S8 * slo.y;
        float az = b4.z + S8 * shi.x;
        float aw = b4.w + S8 * shi.y;
        #pragma unroll
        for (int k = 0; k < KN; ++k) {
            const float w = __shfl(wA[s], qq * 16 + k);
            const f32x2 lo = __builtin_amdgcn_cvt_pk_f32_fp8(nvA[s][k], false);
            const f32x2 hi = __builtin_amdgcn_cvt_pk_f32_fp8(nvA[s][k], true);
            ax += w * lo.x;
            ay += w * lo.y;
            az += w * hi.x;
            aw += w * hi.y;
        }
        *(float4*)&ev1[(4 * s + qq) * DIM + c4] =
            make_float4(fmaxf(ax, 0.f), fmaxf(ay, 0.f), fmaxf(az, 0.f), fmaxf(aw, 0.f));
    }
    {
        const f32x2 slo = __builtin_amdgcn_cvt_pk_f32_fp8(svA8[3], false);
        const f32x2 shi = __builtin_amdgcn_cvt_pk_f32_fp8(svA8[3], true);
        float ax = b4.x + S8 * slo.x;
        float ay = b4.y + S8 * slo.y;
        float az = b4.z + S8 * shi.x;
        float aw = b4.w + S8 * shi.y;
        #pragma unroll
        for (int k = 0; k < KN; ++k) {
            const float w = __shfl(wA[3], qq * 16 + k);
            const f32x2 lo = __builtin_amdgcn_cvt_pk_f32_fp8(nv3[k], false);
            const f32x2 hi = __builtin_amdgcn_cvt_pk_f32_fp8(nv3[k], true);
            ax += w * lo.x;
            ay += w * lo.y;
            az += w * hi.x;
            aw += w * hi.y;
        }
        *(float4*)&ev1[(12 + qq) * DIM + c4] =
            make_float4(fmaxf(ax, 0.f), fmaxf(ay, 0.f), fmaxf(az, 0.f), fmaxf(aw, 0.f));
    }

    // ---- hop 0, layer 0: accumulate the preloaded fp8 rows ----
    float ax = 0.f, ay = 0.f, az = 0.f, aw = 0.f;
    #pragma unroll
    for (int k = 0; k < 4; ++k) {
        const float w = __shfl(w0, qq * 4 + k) * S8;
        const f32x2 lo = __builtin_amdgcn_cvt_pk_f32_fp8(h0v8[k], false);
        const f32x2 hi = __builtin_amdgcn_cvt_pk_f32_fp8(h0v8[k], true);
        ax += w * lo.x;
        ay += w * lo.y;
        az += w * hi.x;
        aw += w * hi.y;
    }
    ax += __shfl_xor(ax, 16); ay += __shfl_xor(ay, 16);
    az += __shfl_xor(az, 16); aw += __shfl_xor(aw, 16);
    ax += __shfl_xor(ax, 32); ay += __shfl_xor(ay, 32);
    az += __shfl_xor(az, 32); aw += __shfl_xor(aw, 32);
    {
        const f32x2 ilo = __builtin_amdgcn_cvt_pk_f32_fp8(itemv8, false);
        const f32x2 ihi = __builtin_amdgcn_cvt_pk_f32_fp8(itemv8, true);
        ax += S8 * ilo.x + b4.x;
        ay += S8 * ilo.y + b4.y;
        az += S8 * ihi.x + b4.z;
        aw += S8 * ihi.y + b4.w;
    }
    const float e0x = fmaxf(ax, 0.f), e0y = fmaxf(ay, 0.f);
    const float e0z = fmaxf(az, 0.f), e0w = fmaxf(aw, 0.f);

    // ---- layer 1 aggregate: x1 = e0 + sum_k w0_k * ev1_k (f32, unscaled w0)
    asm volatile("s_waitcnt lgkmcnt(0)" ::: "memory");  // ev1 writes done (wave-local)
    float sx = 0.f, sy = 0.f, sz = 0.f, sw = 0.f;
    #pragma unroll
    for (int k = 0; k < 4; ++k) {
        const int   kg = qq * 4 + k;
        const float w  = __shfl(w0, kg);
        float4 ev = *(const float4*)&ev1[kg * DIM + c4];
        sx += w * ev.x;
        sy += w * ev.y;
        sz += w * ev.z;
        sw += w * ev.w;
    }
    sx += __shfl_xor(sx, 16); sy += __shfl_xor(sy, 16);
    sz += __shfl_xor(sz, 16); sw += __shfl_xor(sw, 16);
    sx += __shfl_xor(sx, 32); sy += __shfl_xor(sy, 32);
    sz += __shfl_xor(sz, 32); sw += __shfl_xor(sw, 32);

    // ---- the ONE real matvec: h1 = W x1 + b, via LDS broadcast ----
    asm volatile("s_waitcnt lgkmcnt(0)" ::: "memory");
    if (qq == 0)
        *(float4*)&xb[c4] = make_float4(e0x + sx, e0y + sy, e0z + sz, e0w + sw);
    asm volatile("s_waitcnt lgkmcnt(0)" ::: "memory");
    float h0 = bias[lane], h1 = 0.f, h2 = 0.f, h3 = 0.f;
    {
        const float4* Wl  = (const float4*)(W + lane * DIM);
        const float4* xv4 = (const float4*)xb;
        #pragma unroll
        for (int j = 0; j < 16; j += 4) {
            float4 w0v = Wl[j],   x0v = xv4[j];
            float4 w1v = Wl[j+1], x1v = xv4[j+1];
            float4 w2v = Wl[j+2], x2v = xv4[j+2];
            float4 w3v = Wl[j+3], x3v = xv4[j+3];
            h0 += w0v.x*x0v.x + w0v.y*x0v.y + w0v.z*x0v.z + w0v.w*x0v.w;
            h1 += w1v.x*x1v.x + w1v.y*x1v.y + w1v.z*x1v.z + w1v.w*x1v.w;
            h2 += w2v.x*x2v.x + w2v.y*x2v.y + w2v.z*x2v.z + w2v.w*x2v.w;
            h3 += w3v.x*x3v.x + w3v.y*x3v.y + w3v.z*x3v.z + w3v.w*x3v.w;
        }
    }
    const float itemf = tanhf((h0 + h1) + (h2 + h3));

    float d = user_emb[(size_t)user * DIM + lane] * itemf;
    d += __shfl_xor(d, 1);
    d += __shfl_xor(d, 2);
    d += __shfl_xor(d, 4);
    d += __shfl_xor(d, 8);
    d += __shfl_xor(d, 16);
    d += __shfl_xor(d, 32);
    if (lane == 0) out[p] = 1.f / (1.f + expf(-d));
}

// ============================================================================
// Fallback (verified R5 kernel) in case ws_size < table sizes.
// ============================================================================
__global__ __launch_bounds__(256, 4) void kgcn_fallback(
    const int* __restrict__ pairs, const int* __restrict__ adj_entity,
    const int* __restrict__ adj_relation, const float* __restrict__ entity_emb,
    const float* __restrict__ relation_emb, const float* __restrict__ user_emb,
    const float* __restrict__ W, const float* __restrict__ bias,
    float* __restrict__ out, int nPairs)
{
    __shared__ float ev1_s[2][KN * DIM];
    __shared__ float xb_s[4][DIM];
    const int tid = threadIdx.x, wave = tid >> 6, lane = tid & 63;
    const int q = wave >> 1, half = wave & 1;
    int p = blockIdx.x * 2 + q;
    if (p >= nPairs) p = nPairs - 1;
    float* ev1 = ev1_s[q]; float* xb = xb_s[wave];
    const int user = pairs[2 * p + 0], item = pairs[2 * p + 1];
    const float bval = bias[lane];
    const float* emb_l = entity_emb + lane;
    const float4* W4 = (const float4*)(W + lane * DIM);
    int rk0 = 0, e1 = 0;
    if (lane < KN) {
        rk0 = adj_relation[(size_t)item * KN + lane];
        e1  = adj_entity[(size_t)item * KN + lane];
    }
    float acc;
    {
        const int r = lane >> 1, hlf = lane & 1;
        const float4* rel4 = (const float4*)(relation_emb + r * DIM + hlf * 32);
        const float4* u4 = (const float4*)(user_emb + (size_t)user * DIM + hlf * 32);
        float a0 = 0.f, a1 = 0.f;
        #pragma unroll
        for (int j = 0; j < 8; j += 2) {
            float4 a = rel4[j], b = u4[j], c = rel4[j+1], d = u4[j+1];
            a0 += a.x*b.x + a.y*b.y + a.z*b.z + a.w*b.w;
            a1 += c.x*d.x + c.y*d.y + c.z*d.z + c.w*d.w;
        }
        acc = a0 + a1; acc += __shfl_xor(acc, 1);
    }
    auto softmax16 = [&](float s) -> float {
        float mx = s;
        mx = fmaxf(mx, __shfl_xor(mx, 1)); mx = fmaxf(mx, __shfl_xor(mx, 2));
        mx = fmaxf(mx, __shfl_xor(mx, 4)); mx = fmaxf(mx, __shfl_xor(mx, 8));
        float e = __expf(s - mx);
        float ss = e;
        ss += __shfl_xor(ss, 1); ss += __shfl_xor(ss, 2);
        ss += __shfl_xor(ss, 4); ss += __shfl_xor(ss, 8);
        return e * frcp(ss);
    };
    auto matvec = [&](float xv) -> float {
        asm volatile("s_waitcnt lgkmcnt(0)" ::: "memory");
        xb[lane] = xv;
        asm volatile("s_waitcnt lgkmcnt(0)" ::: "memory");
        float h0 = bval, h1 = 0.f, h2 = 0.f, h3 = 0.f;
        const float4* xv4 = (const float4*)xb;
        #pragma unroll
        for (int j = 0; j < 16; j += 4) {
            float4 w0 = W4[j], x0 = xv4[j], w1 = W4[j+1], x1 = xv4[j+1];
            float4 w2 = W4[j+2], x2 = xv4[j+2], w3 = W4[j+3], x3 = xv4[j+3];
            h0 += w0.x*x0.x + w0.y*x0.y + w0.z*x0.z + w0.w*x0.w;
            h1 += w1.x*x1.x + w1.y*x1.y + w1.z*x1.z + w1.w*x1.w;
            h2 += w2.x*x2.x + w2.y*x2.y + w2.z*x2.z + w2.w*x2.w;
            h3 += w3.x*x3.x + w3.y*x3.y + w3.z*x3.z + w3.w*x3.w;
        }
        return (h0 + h1) + (h2 + h3);
    };
    auto gather = [&](int self, int ek, float w) -> float {
        float xa = emb_l[(size_t)(unsigned)self * DIM], xc = 0.f;
        #pragma unroll
        for (int k = 0; k < KN; k += 2) {
            const int e0i = __shfl(ek, k); const float f0 = __shfl(w, k);
            const int e1i = __shfl(ek, k + 1); const float f1 = __shfl(w, k + 1);
            xa += f0 * emb_l[(size_t)(unsigned)e0i * DIM];
            xc += f1 * emb_l[(size_t)(unsigned)e1i * DIM];
        }
        return xa + xc;
    };
    int rk_n = 0, ek_n = 0;
    {
        const int g0 = __shfl(e1, half * 8);
        if (lane < KN) {
            rk_n = adj_relation[(size_t)(unsigned)g0 * KN + lane];
            ek_n = adj_entity[(size_t)(unsigned)g0 * KN + lane];
        }
    }
    #pragma unroll 1
    for (int mi = 0; mi < 8; ++mi) {
        const int m = half * 8 + mi;
        const int g = __shfl(e1, m);
        const int rk = rk_n, ek = ek_n;
        if (mi + 1 < 8) {
            const int gn = __shfl(e1, m + 1);
            if (lane < KN) {
                rk_n = adj_relation[(size_t)(unsigned)gn * KN + lane];
                ek_n = adj_entity[(size_t)(unsigned)gn * KN + lane];
            }
        }
        const float w = softmax16(__shfl(acc, rk << 1));
        const float x = gather(g, ek, w);
        ev1[m * DIM + lane] = fmaxf(matvec(x), 0.f);
    }
    __syncthreads();
    if (half != 0) return;
    const float w0 = softmax16(__shfl(acc, rk0 << 1));
    const float x0 = gather(item, e1, w0);
    const float e0 = fmaxf(matvec(x0), 0.f);
    float xa = e0, xc = 0.f;
    #pragma unroll
    for (int k = 0; k < KN; k += 2) {
        xa += __shfl(w0, k) * ev1[k * DIM + lane];
        xc += __shfl(w0, k + 1) * ev1[(k + 1) * DIM + lane];
    }
    const float itemf = tanhf(matvec(xa + xc));
    float d = user_emb[(size_t)user * DIM + lane] * itemf;
    d += __shfl_xor(d, 1); d += __shfl_xor(d, 2); d += __shfl_xor(d, 4);
    d += __shfl_xor(d, 8); d += __shfl_xor(d, 16); d += __shfl_xor(d, 32);
    if (lane == 0) out[p] = 1.f / (1.f + expf(-d));
}

extern "C" void kernel_launch(void* const* d_in, const int* in_sizes, int n_in,
                              void* d_out, int out_size, void* d_ws, size_t ws_size,
                              hipStream_t stream) {
    const int*   pairs        = (const int*)d_in[0];
    const int*   adj_entity   = (const int*)d_in[1];
    const int*   adj_relation = (const int*)d_in[2];
    const float* entity_emb   = (const float*)d_in[3];
    const float* relation_emb = (const float*)d_in[4];
    const float* user_emb     = (const float*)d_in[5];
    const float* W            = (const float*)d_in[6];
    const float* b            = (const float*)d_in[7];
    float* out = (float*)d_out;

    const int nPairs = in_sizes[0] / 2;          // pairs is (B, 2)
    const int nEnt   = in_sizes[3] / DIM;        // entity count
    const size_t w8Bytes   = (size_t)in_sizes[3] * sizeof(unsigned char);
    const size_t w8Aligned = (w8Bytes + 255) & ~(size_t)255;
    const size_t adjBytes  = (size_t)nEnt * KN * sizeof(int);

    if (ws_size >= w8Aligned + adjBytes) {
        unsigned char* WE8 = (unsigned char*)d_ws;
        int* adjP = (int*)((char*)d_ws + w8Aligned);
        const int nTiles = (nEnt + 15) >> 4;
        const int preBlocks = (nTiles + 7) / 8;   // 2 tiles/wave, 4 waves/block
        we_kernel_mfma<<<preBlocks, 256, 0, stream>>>(entity_emb, W,
                                                      adj_entity, adj_relation,
                                                      WE8, adjP, nEnt);
        const int mainBlocks = (nPairs + 3) / 4;  // 1 wave/pair
        kgcn_main<<<mainBlocks, 256, 0, stream>>>(pairs, adjP,
                                                  WE8, relation_emb, user_emb,
                                                  W, b, out, nPairs);
    } else {
        const int nBlocks = (nPairs + 1) / 2;
        kgcn_fallback<<<nBlocks, 256, 0, stream>>>(pairs, adj_entity, adj_relation,
                                                   entity_emb, relation_emb, user_emb,
                                                   W, b, out, nPairs);
    }
}